// Round 4
// baseline (14040.062 us; speedup 1.0000x reference)
//
#include <hip/hip_runtime.h>
#include <math.h>

typedef __bf16 bf16;
typedef __bf16 bf16x8 __attribute__((ext_vector_type(8)));

// ---------- dtype-agnostic access (runtime probe on ln_g == ones) ----------
__device__ __forceinline__ bool probe_f32(const void* g) {
  return ((const unsigned*)g)[0] == 0x3F800000u;   // fp32 1.0; bf16 pair = 0x3F803F80
}
__device__ __forceinline__ float ldf(const void* p, size_t i, bool f32) {
  return f32 ? ((const float*)p)[i] : (float)((const bf16*)p)[i];
}
__device__ __forceinline__ void stf(void* p, size_t i, bool f32, float v) {
  if (f32) ((float*)p)[i] = v; else ((bf16*)p)[i] = (bf16)v;
}

// ---------- block reductions (256 threads, 4 waves) ----------
__device__ __forceinline__ float bred_sum(float v, volatile float* red, int tid) {
  for (int off = 32; off; off >>= 1) v += __shfl_down(v, off, 64);
  __syncthreads();
  if ((tid & 63) == 0) red[tid >> 6] = v;
  __syncthreads();
  float r = red[0] + red[1] + red[2] + red[3];
  __syncthreads();
  return r;
}
__device__ __forceinline__ float bred_max(float v, volatile float* red, int tid) {
  for (int off = 32; off; off >>= 1) v = fmaxf(v, __shfl_down(v, off, 64));
  __syncthreads();
  if ((tid & 63) == 0) red[tid >> 6] = v;
  __syncthreads();
  float r = fmaxf(fmaxf(red[0], red[1]), fmaxf(red[2], red[3]));
  __syncthreads();
  return r;
}

// ---------- QKV for heads [h0, h0+nh): per-token block, LN + partial gemm ----------
__global__ __launch_bounds__(256) void qkv_head_kernel(const void* __restrict__ x,
    const void* __restrict__ g, const void* __restrict__ b, const void* __restrict__ w,
    bf16* __restrict__ q, bf16* __restrict__ k, bf16* __restrict__ v, int h0, int nh) {
  __shared__ float nr[768];
  __shared__ float red[4];
  const bool f32 = probe_f32(g);
  const int tok = blockIdx.x, tid = threadIdx.x;
  const size_t xb = (size_t)tok * 768;
  float s = 0.f, ss = 0.f;
  for (int i = tid; i < 768; i += 256) { float vv = ldf(x, xb + i, f32); s += vv; ss += vv * vv; }
  s = bred_sum(s, red, tid); ss = bred_sum(ss, red, tid);
  float mu = s * (1.f / 768.f);
  float rstd = rsqrtf(ss * (1.f / 768.f) - mu * mu + 1e-5f);
  for (int i = tid; i < 768; i += 256)
    nr[i] = (ldf(x, xb + i, f32) - mu) * rstd * ldf(g, i, f32) + ldf(b, i, f32);
  __syncthreads();
  const int bb = tok >> 11, tt = tok & 2047;
  const int ncols = 192 * nh;
  for (int cl = tid; cl < ncols; cl += 256) {
    int which = cl / (64 * nh);
    int r = cl - which * 64 * nh;
    int d = r / nh, hl = r - d * nh;
    int wcol = which * 768 + d * 12 + (h0 + hl);
    float acc = 0.f;
    for (int e = 0; e < 768; ++e) acc += nr[e] * ldf(w, (size_t)e * 2304 + wcol, f32);
    bf16* dst = which == 0 ? q : (which == 1 ? k : v);
    dst[((size_t)((bb * nh + hl) * 2048 + tt)) * 64 + d] = (bf16)acc;
  }
}

// ---------- Attention over compact q/k/v (nh heads); writes into d_out at final spot ----
__global__ __launch_bounds__(256) void attn_kernel(const bf16* __restrict__ q,
    const bf16* __restrict__ k, const bf16* __restrict__ v, void* __restrict__ out,
    const void* __restrict__ g, int h0, int nh) {
  __shared__ float S[4][2048];
  __shared__ float qr[4][64];
  __shared__ float red[4];
  __shared__ float part[4][4][64];
  const bool f32 = probe_f32(g);
  const int tid = threadIdx.x;
  const int bhl = blockIdx.y, q0 = blockIdx.x * 4;
  const int bb = bhl / nh, hl = bhl - bb * nh;
  const size_t base = (size_t)bhl * 2048 * 64;
  { int r = tid >> 6, d = tid & 63;
    qr[r][d] = (float)q[base + (size_t)(q0 + r) * 64 + d]; }
  __syncthreads();
  float acc[4][8];
  for (int r = 0; r < 4; ++r) for (int m = 0; m < 8; ++m) acc[r][m] = 0.f;
  for (int oct = 0; oct < 8; ++oct) {
    float qe[4][8];
    for (int r = 0; r < 4; ++r)
      for (int e = 0; e < 8; ++e) qe[r][e] = qr[r][oct * 8 + e];
    for (int m = 0; m < 8; ++m) {
      int j = tid + (m << 8);
      bf16x8 kv = *(const bf16x8*)&k[base + (size_t)j * 64 + oct * 8];
      for (int e = 0; e < 8; ++e) {
        float kf = (float)kv[e];
        for (int r = 0; r < 4; ++r) acc[r][m] += qe[r][e] * kf;
      }
    }
  }
  float ls[4];
  for (int r = 0; r < 4; ++r) {
    float lm = -1e30f;
    for (int m = 0; m < 8; ++m) { acc[r][m] *= 0.125f; lm = fmaxf(lm, acc[r][m]); }
    float mr = bred_max(lm, red, tid);
    float lsum = 0.f;
    for (int m = 0; m < 8; ++m) {
      float p = expf(acc[r][m] - mr);
      S[r][tid + (m << 8)] = p;
      lsum += p;
    }
    ls[r] = bred_sum(lsum, red, tid);
  }
  __syncthreads();
  const int d = tid & 63, pt = tid >> 6;
  float ov[4];
  for (int r = 0; r < 4; ++r) ov[r] = 0.f;
  for (int j = pt * 512; j < pt * 512 + 512; ++j) {
    float vf = (float)v[base + (size_t)j * 64 + d];
    for (int r = 0; r < 4; ++r) ov[r] += S[r][j] * vf;
  }
  for (int r = 0; r < 4; ++r) part[pt][r][d] = ov[r];
  __syncthreads();
  if (pt == 0) {
    for (int r = 0; r < 4; ++r) {
      float sum = part[0][r][d] + part[1][r][d] + part[2][r][d] + part[3][r][d];
      stf(out, ((size_t)(bb * 2048) + (q0 + r)) * 768 + (h0 + hl) * 64 + d, f32,
          sum / ls[r]);
    }
  }
}

// ---------- Fused: read at-row from d_out, proj+residual, LN, MLP, write d_out ----------
__global__ __launch_bounds__(256) void mlp_kernel(const void* __restrict__ x,
    const void* __restrict__ g, const void* __restrict__ b,
    const void* __restrict__ wao, const void* __restrict__ wi, const void* __restrict__ bi,
    const void* __restrict__ wo, const void* __restrict__ bo, void* __restrict__ out) {
  __shared__ float ar[768];
  __shared__ float nr[768];
  __shared__ float x1l[768];
  __shared__ float hl3[3072];
  __shared__ float red[4];
  const bool f32 = probe_f32(g);
  const int tok = blockIdx.x, tid = threadIdx.x;
  const size_t xb = (size_t)tok * 768;
  // attention output (staged by attn_kernel at the final out position/dtype)
  for (int i = tid; i < 768; i += 256) ar[i] = ldf(out, xb + i, f32);
  // LayerNorm of x
  float s = 0.f, ss = 0.f;
  for (int i = tid; i < 768; i += 256) { float vv = ldf(x, xb + i, f32); s += vv; ss += vv * vv; }
  s = bred_sum(s, red, tid); ss = bred_sum(ss, red, tid);
  float mu = s * (1.f / 768.f);
  float rstd = rsqrtf(ss * (1.f / 768.f) - mu * mu + 1e-5f);
  for (int i = tid; i < 768; i += 256)
    nr[i] = (ldf(x, xb + i, f32) - mu) * rstd * ldf(g, i, f32) + ldf(b, i, f32);
  __syncthreads();
  // x1 = x + at @ w_ao   (3 cols/thread)
  for (int m = 0; m < 3; ++m) {
    int col = tid + (m << 8);
    float a = 0.f;
    for (int e = 0; e < 768; ++e) a += ar[e] * ldf(wao, (size_t)e * 768 + col, f32);
    x1l[col] = ldf(x, xb + col, f32) + a;
  }
  // h = gelu(nr @ w_in + b_in)   (12 cols/thread)
  for (int m = 0; m < 12; ++m) {
    int col = tid + (m << 8);
    float a = 0.f;
    for (int e = 0; e < 768; ++e) a += nr[e] * ldf(wi, (size_t)e * 3072 + col, f32);
    a += ldf(bi, col, f32);
    hl3[col] = 0.5f * a * (1.f + erff(a * 0.70710678118654752f));
  }
  __syncthreads();
  // out = x1 + h @ w_out + b_out   (3 cols/thread)
  for (int m = 0; m < 3; ++m) {
    int col = tid + (m << 8);
    float a = 0.f;
    for (int e = 0; e < 3072; ++e) a += hl3[e] * ldf(wo, (size_t)e * 768 + col, f32);
    stf(out, xb + col, f32, x1l[col] + a + ldf(bo, col, f32));
  }
}

// ---------- launch ----------
extern "C" void kernel_launch(void* const* d_in, const int* in_sizes, int n_in,
                              void* d_out, int out_size, void* d_ws, size_t ws_size,
                              hipStream_t stream) {
  // Identify inputs by element count; tolerate byte-counts (x2 bf16 / x4 fp32).
  static const long expected[9] = {6291456, 768, 768, 1769472, 589824, 2359296,
                                   3072, 2359296, 768};
  long f = 1;
  bool found = false;
  for (long ff = 1; ff <= 4 && !found; ff *= 2)
    for (int i = 0; i < n_in; ++i)
      if ((long)in_sizes[i] == 6291456L * ff) { f = ff; found = true; break; }
  int idx[9];
  bool used[32] = {false};
  for (int s = 0; s < 9; ++s) {
    idx[s] = -1;
    if (found)
      for (int i = 0; i < n_in; ++i)
        if (!used[i] && (long)in_sizes[i] == expected[s] * f) { idx[s] = i; used[i] = true; break; }
    if (idx[s] < 0) idx[s] = s;   // fallback: dict order
  }
  const void* x    = d_in[idx[0]];
  const void* ln_g = d_in[idx[1]];
  const void* ln_b = d_in[idx[2]];
  const void* wqkv = d_in[idx[3]];
  const void* wao  = d_in[idx[4]];
  const void* wi   = d_in[idx[5]];
  const void* bi   = d_in[idx[6]];
  const void* wo   = d_in[idx[7]];
  const void* bo   = d_in[idx[8]];

  // Heads per pass limited by ws_size: q+k+v per head = 3*4*2048*64*2 B = 3,145,728 B.
  const size_t per_head = 3145728;
  int hpp = (int)(ws_size / per_head);
  if (hpp < 1) hpp = 1;
  if (hpp > 12) hpp = 12;
  const size_t hb = (size_t)hpp * 1048576;   // bytes per q/k/v region
  bf16* qb = (bf16*)((char*)d_ws + 0);
  bf16* kb = (bf16*)((char*)d_ws + hb);
  bf16* vb = (bf16*)((char*)d_ws + 2 * hb);

  for (int h0 = 0; h0 < 12; h0 += hpp) {
    int nh = 12 - h0 < hpp ? 12 - h0 : hpp;
    qkv_head_kernel<<<8192, 256, 0, stream>>>(x, ln_g, ln_b, wqkv, qb, kb, vb, h0, nh);
    attn_kernel<<<dim3(512, 4 * nh), 256, 0, stream>>>(qb, kb, vb, d_out, ln_g, h0, nh);
  }
  mlp_kernel<<<8192, 256, 0, stream>>>(x, ln_g, ln_b, wao, wi, bi, wo, bo, d_out);
}

// Round 5
// 765.705 us; speedup vs baseline: 18.3361x; 18.3361x over previous
//
#include <hip/hip_runtime.h>
#include <math.h>

typedef __bf16 bf16;
typedef __bf16 bf16x8 __attribute__((ext_vector_type(8)));
typedef __bf16 bf16x4 __attribute__((ext_vector_type(4)));
typedef float  f32x4  __attribute__((ext_vector_type(4)));

#define MFMA16(a, b, c) __builtin_amdgcn_mfma_f32_16x16x32_bf16((a), (b), (c), 0, 0, 0)

// direct global->LDS, 16B/lane; lds dest = wave-uniform base + lane*16
__device__ __forceinline__ void async_copy16(const bf16* g, bf16* l) {
  __builtin_amdgcn_global_load_lds((const __attribute__((address_space(1))) void*)g,
                                   (__attribute__((address_space(3))) void*)l, 16, 0, 0);
}

// ---------- LayerNorm: fp32 x -> bf16 norm. One block/token, 768 = 256*3 ----------
__global__ __launch_bounds__(256) void ln_kernel(const float* __restrict__ x,
    const float* __restrict__ g, const float* __restrict__ b, bf16* __restrict__ nrm) {
  const int tok = blockIdx.x, t = threadIdx.x;
  const float* xr = x + (size_t)tok * 768;
  float v0 = xr[t], v1 = xr[t + 256], v2 = xr[t + 512];
  float s = v0 + v1 + v2, ss = v0 * v0 + v1 * v1 + v2 * v2;
  for (int off = 32; off; off >>= 1) {
    s += __shfl_down(s, off, 64); ss += __shfl_down(ss, off, 64);
  }
  __shared__ float red[8];
  if ((t & 63) == 0) { red[(t >> 6) * 2] = s; red[(t >> 6) * 2 + 1] = ss; }
  __syncthreads();
  s = red[0] + red[2] + red[4] + red[6];
  ss = red[1] + red[3] + red[5] + red[7];
  float mu = s * (1.f / 768.f);
  float rstd = rsqrtf(ss * (1.f / 768.f) - mu * mu + 1e-5f);
  bf16* o = nrm + (size_t)tok * 768;
  o[t]       = (bf16)((v0 - mu) * rstd * g[t]       + b[t]);
  o[t + 256] = (bf16)((v1 - mu) * rstd * g[t + 256] + b[t + 256]);
  o[t + 512] = (bf16)((v2 - mu) * rstd * g[t + 512] + b[t + 512]);
}

// ---------- cast+transpose: W[K,N] fp32 -> Wt[N,K] bf16 ----------
__global__ __launch_bounds__(256) void castT_kernel(const float* __restrict__ in,
    bf16* __restrict__ out, int K, int N) {
  __shared__ float tile[64][65];
  const int t = threadIdx.x;
  const int r = t >> 4, c4 = (t & 15) * 4;
  const int k0 = blockIdx.y * 64, n0 = blockIdx.x * 64;
  for (int it = 0; it < 4; ++it) {
    int row = r + it * 16;
    const float4 v = *(const float4*)(in + (size_t)(k0 + row) * N + n0 + c4);
    tile[row][c4] = v.x; tile[row][c4 + 1] = v.y;
    tile[row][c4 + 2] = v.z; tile[row][c4 + 3] = v.w;
  }
  __syncthreads();
  for (int it = 0; it < 4; ++it) {
    int row = r + it * 16;     // n-offset
    bf16x4 v;
    for (int j = 0; j < 4; ++j) v[j] = (bf16)tile[c4 + j][row];
    *(bf16x4*)(out + (size_t)(n0 + row) * K + k0 + c4) = v;
  }
}

// ---------- GEMM (m97 structure): C[M,N] = A[M,K]@Bt[N,K]^T, epilogue fused ----------
// RES: +fp32 res. BIAS: +fp32 bias. GELU: exact gelu. OUTF32: fp32 store else bf16.
// SPLIT: qkv scatter to q/k/v [bh][t][d] bf16.
template <int RES, int BIAS, int GELU, int OUTF32, int SPLIT>
__global__ __launch_bounds__(256) void gemm_bt(
    const bf16* __restrict__ A, const bf16* __restrict__ Bt, int ldb,
    void* __restrict__ Cv, const float* __restrict__ bias, const float* __restrict__ res,
    bf16* __restrict__ qo, bf16* __restrict__ ko, bf16* __restrict__ vo,
    int M, int N, int K) {
  __shared__ bf16 As[4096];   // [128][32]
  __shared__ bf16 Bs[4096];   // [128][32]
  const int t = threadIdx.x;
  const int l = t & 63, w = t >> 6;
  const int lr = l >> 4, lc = l & 15;
  const int wm = w >> 1, wn = w & 1;
  const int m0 = blockIdx.y * 128, n0 = blockIdx.x * 128;

  const int srow = w * 16 + (l >> 2);     // 16 rows per wave
  const int scol = (l & 3) * 8;           // 4 octets cover 32 k
  const bf16* ga0 = A  + (size_t)(m0 + srow) * K + scol;
  const bf16* ga1 = A  + (size_t)(m0 + 64 + srow) * K + scol;
  const bf16* gb0 = Bt + (size_t)(n0 + srow) * ldb + scol;
  const bf16* gb1 = Bt + (size_t)(n0 + 64 + srow) * ldb + scol;
  bf16* la0 = &As[w * 512];
  bf16* la1 = &As[2048 + w * 512];
  bf16* lb0 = &Bs[w * 512];
  bf16* lb1 = &Bs[2048 + w * 512];

  f32x4 acc[4][4];
  for (int i = 0; i < 4; ++i)
    for (int j = 0; j < 4; ++j) acc[i][j] = (f32x4){0.f, 0.f, 0.f, 0.f};

  for (int k0 = 0; k0 < K; k0 += 32) {
    async_copy16(ga0 + k0, la0);
    async_copy16(ga1 + k0, la1);
    async_copy16(gb0 + k0, lb0);
    async_copy16(gb1 + k0, lb1);
    __syncthreads();
    bf16x8 af[4], bfr[4];
    for (int i = 0; i < 4; ++i)
      af[i] = *(const bf16x8*)&As[(wm * 64 + i * 16 + lc) * 32 + 8 * lr];
    for (int j = 0; j < 4; ++j)
      bfr[j] = *(const bf16x8*)&Bs[(wn * 64 + j * 16 + lc) * 32 + 8 * lr];
    for (int i = 0; i < 4; ++i)
      for (int j = 0; j < 4; ++j)
        acc[i][j] = MFMA16(af[i], bfr[j], acc[i][j]);
    __syncthreads();
  }

  const size_t Ns = (size_t)N;
  for (int i = 0; i < 4; ++i) {
    int rowb = m0 + wm * 64 + i * 16 + lr * 4;
    for (int j = 0; j < 4; ++j) {
      int col = n0 + wn * 64 + j * 16 + lc;
      float bv = BIAS ? bias[col] : 0.f;
      for (int r = 0; r < 4; ++r) {
        int row = rowb + r;
        float vv = acc[i][j][r];
        if (BIAS) vv += bv;
        if (GELU) vv = 0.5f * vv * (1.f + erff(vv * 0.70710678118654752f));
        if (RES)  vv += res[(size_t)row * Ns + col];
        if (SPLIT) {
          int which = col / 768;
          int rem = col - which * 768;
          int d = rem / 12, h = rem - d * 12;
          int bb = row >> 11, tt = row & 2047;
          bf16* dst = which == 0 ? qo : (which == 1 ? ko : vo);
          dst[((size_t)((bb * 12 + h) * 2048 + tt)) * 64 + d] = (bf16)vv;
        } else if (OUTF32) {
          ((float*)Cv)[(size_t)row * Ns + col] = vv;
        } else {
          ((bf16*)Cv)[(size_t)row * Ns + col] = (bf16)vv;
        }
      }
    }
  }
}

// ---------- Flash attention (MFMA): block = (bh, 64 q rows), 4 waves x 16 rows ----------
__global__ __launch_bounds__(256) void attn_kernel(const bf16* __restrict__ q,
    const bf16* __restrict__ k, const bf16* __restrict__ v, bf16* __restrict__ out) {
  __shared__ bf16 Ks[32 * 72];     // [key][72 pad]
  __shared__ bf16 Vt[64 * 40];     // [d][40 pad, key octet-rotated by (d>>3)&3]
  __shared__ bf16 Ps[4 * 16 * 40]; // per-wave P: [16 rows][40]
  const int t = threadIdx.x;
  const int l = t & 63, w = t >> 6;
  const int g = l >> 4, c = l & 15;
  const int bh = blockIdx.y;
  const int q0 = blockIdx.x * 64;
  const size_t base = (size_t)bh * (2048 * 64);
  bf16x8 aq0 = *(const bf16x8*)(q + base + (size_t)(q0 + w * 16 + c) * 64 + 8 * g);
  bf16x8 aq1 = *(const bf16x8*)(q + base + (size_t)(q0 + w * 16 + c) * 64 + 32 + 8 * g);
  f32x4 O[4];
  for (int j = 0; j < 4; ++j) O[j] = (f32x4){0.f, 0.f, 0.f, 0.f};
  float m_i[4], l_i[4];
  for (int r = 0; r < 4; ++r) { m_i[r] = -1e30f; l_i[r] = 0.f; }
  const int sr = t >> 3, so = t & 7;
  const float cs = 0.125f * 1.44269504089f;   // scale * log2(e)

  for (int j0 = 0; j0 < 2048; j0 += 32) {
    __syncthreads();
    bf16x8 kv = *(const bf16x8*)(k + base + (size_t)(j0 + sr) * 64 + so * 8);
    bf16x8 vv = *(const bf16x8*)(v + base + (size_t)(j0 + sr) * 64 + so * 8);
    *(bf16x8*)&Ks[sr * 72 + so * 8] = kv;
    for (int i = 0; i < 8; ++i) {
      int dd = so * 8 + i;
      Vt[dd * 40 + ((sr + ((dd >> 3) & 3) * 8) & 31)] = vv[i];
    }
    __syncthreads();
    f32x4 S0 = (f32x4){0.f, 0.f, 0.f, 0.f};
    f32x4 S1 = S0;
    {
      bf16x8 b00 = *(const bf16x8*)&Ks[c * 72 + 8 * g];
      bf16x8 b01 = *(const bf16x8*)&Ks[c * 72 + 32 + 8 * g];
      S0 = MFMA16(aq0, b00, S0); S0 = MFMA16(aq1, b01, S0);
      bf16x8 b10 = *(const bf16x8*)&Ks[(16 + c) * 72 + 8 * g];
      bf16x8 b11 = *(const bf16x8*)&Ks[(16 + c) * 72 + 32 + 8 * g];
      S1 = MFMA16(aq0, b10, S1); S1 = MFMA16(aq1, b11, S1);
    }
    float mx[4];
    for (int r = 0; r < 4; ++r) {
      S0[r] *= cs; S1[r] *= cs;
      mx[r] = fmaxf(S0[r], S1[r]);
    }
    for (int off = 1; off < 16; off <<= 1)
      for (int r = 0; r < 4; ++r) mx[r] = fmaxf(mx[r], __shfl_xor(mx[r], off, 64));
    float alpha[4], rs_[4];
    for (int r = 0; r < 4; ++r) {
      float mn = fmaxf(m_i[r], mx[r]);
      alpha[r] = exp2f(m_i[r] - mn);
      m_i[r] = mn;
      rs_[r] = 0.f;
    }
    for (int r = 0; r < 4; ++r) {
      float p0 = exp2f(S0[r] - m_i[r]);
      float p1 = exp2f(S1[r] - m_i[r]);
      bf16 pb0 = (bf16)p0, pb1 = (bf16)p1;
      Ps[w * 640 + (g * 4 + r) * 40 + c] = pb0;
      Ps[w * 640 + (g * 4 + r) * 40 + 16 + c] = pb1;
      rs_[r] += (float)pb0 + (float)pb1;
    }
    for (int off = 1; off < 16; off <<= 1)
      for (int r = 0; r < 4; ++r) rs_[r] += __shfl_xor(rs_[r], off, 64);
    for (int r = 0; r < 4; ++r) l_i[r] = l_i[r] * alpha[r] + rs_[r];
    for (int j = 0; j < 4; ++j)
      for (int r = 0; r < 4; ++r) O[j][r] *= alpha[r];
    __syncthreads();
    bf16x8 ap = *(const bf16x8*)&Ps[w * 640 + c * 40 + 8 * g];
    for (int j = 0; j < 4; ++j) {
      int dd = j * 16 + c;
      bf16x8 bv = *(const bf16x8*)&Vt[dd * 40 + ((8 * g + ((dd >> 3) & 3) * 8) & 31)];
      O[j] = MFMA16(ap, bv, O[j]);
    }
  }
  const int b = bh / 12, h = bh % 12;
  for (int j = 0; j < 4; ++j)
    for (int r = 0; r < 4; ++r) {
      int tok = q0 + w * 16 + g * 4 + r;
      int col = h * 64 + j * 16 + c;
      out[(size_t)(b * 2048 + tok) * 768 + col] = (bf16)(O[j][r] / l_i[r]);
    }
}

// ---------- launch ----------
extern "C" void kernel_launch(void* const* d_in, const int* in_sizes, int n_in,
                              void* d_out, int out_size, void* d_ws, size_t ws_size,
                              hipStream_t stream) {
  // input identification by element count (proven in R4); fallback dict order
  static const long expected[9] = {6291456, 768, 768, 1769472, 589824, 2359296,
                                   3072, 2359296, 768};
  long f = 1; bool found = false;
  for (long ff = 1; ff <= 4 && !found; ff *= 2)
    for (int i = 0; i < n_in; ++i)
      if ((long)in_sizes[i] == 6291456L * ff) { f = ff; found = true; break; }
  int idx[9]; bool used[32] = {false};
  for (int s = 0; s < 9; ++s) {
    idx[s] = -1;
    if (found)
      for (int i = 0; i < n_in; ++i)
        if (!used[i] && (long)in_sizes[i] == expected[s] * f) { idx[s] = i; used[i] = true; break; }
    if (idx[s] < 0) idx[s] = s;
  }
  const float* x    = (const float*)d_in[idx[0]];
  const float* ln_g = (const float*)d_in[idx[1]];
  const float* ln_b = (const float*)d_in[idx[2]];
  const float* wqkv = (const float*)d_in[idx[3]];
  const float* wao  = (const float*)d_in[idx[4]];
  const float* wi   = (const float*)d_in[idx[5]];
  const float* bi   = (const float*)d_in[idx[6]];
  const float* wo   = (const float*)d_in[idx[7]];
  const float* bo   = (const float*)d_in[idx[8]];

  // ws map (MiB): norm[0,12) | wtq[12,15.375) then at[12,24) then hq[12,24)
  //               | q[24,36) then wta[24,25.125) wti[25.125,29.625) wto[29.625,34.125)
  // d_out map:    k[0,12) v[12,24) bf16, then x1 fp32 [0,24) (also final out)
  char* ws = (char*)d_ws;
  const size_t MiB = 1048576;
  bf16*  norm = (bf16*)(ws);
  bf16*  wtq  = (bf16*)(ws + 12 * MiB);
  bf16*  at   = (bf16*)(ws + 12 * MiB);
  bf16*  hq   = (bf16*)(ws + 12 * MiB);
  bf16*  qb   = (bf16*)(ws + 24 * MiB);
  bf16*  wta  = (bf16*)(ws + 24 * MiB);
  bf16*  wti  = (bf16*)(ws + 24 * MiB + 1179648);
  bf16*  wto  = (bf16*)(ws + 24 * MiB + 1179648 + 4718592);
  bf16*  kb   = (bf16*)d_out;
  bf16*  vb   = (bf16*)((char*)d_out + 12 * MiB);
  float* x1   = (float*)d_out;

  ln_kernel<<<8192, 256, 0, stream>>>(x, ln_g, ln_b, norm);
  castT_kernel<<<dim3(36, 12), 256, 0, stream>>>(wqkv, wtq, 768, 2304);
  // qkv = norm @ w_qkv, scattered to q(ws)/k,v(d_out) [bh][t][d] bf16
  gemm_bt<0,0,0,0,1><<<dim3(18, 64), 256, 0, stream>>>(
      norm, wtq, 768, nullptr, nullptr, nullptr, qb, kb, vb, 8192, 2304, 768);
  attn_kernel<<<dim3(32, 48), 256, 0, stream>>>(qb, kb, vb, at);
  // weight casts into dead-q region
  castT_kernel<<<dim3(12, 12), 256, 0, stream>>>(wao, wta, 768, 768);
  castT_kernel<<<dim3(48, 12), 256, 0, stream>>>(wi,  wti, 768, 3072);
  castT_kernel<<<dim3(12, 48), 256, 0, stream>>>(wo,  wto, 3072, 768);
  // x1 = x + at @ w_attn_out  (fp32, into d_out; k/v dead)
  gemm_bt<1,0,0,1,0><<<dim3(6, 64), 256, 0, stream>>>(
      at, wta, 768, x1, nullptr, x, nullptr, nullptr, nullptr, 8192, 768, 768);
  // MLP in 4 K-slices: hq = gelu(norm @ wi_p + bi_p); x1 += hq @ wo_p (+b_out last)
  for (int p = 0; p < 4; ++p) {
    gemm_bt<0,1,1,0,0><<<dim3(6, 64), 256, 0, stream>>>(
        norm, wti + (size_t)p * 768 * 768, 768, hq, bi + p * 768, nullptr,
        nullptr, nullptr, nullptr, 8192, 768, 768);
    if (p < 3)
      gemm_bt<1,0,0,1,0><<<dim3(6, 64), 256, 0, stream>>>(
          hq, wto + (size_t)p * 768, 3072, x1, nullptr, x1,
          nullptr, nullptr, nullptr, 8192, 768, 768);
    else
      gemm_bt<1,1,0,1,0><<<dim3(6, 64), 256, 0, stream>>>(
          hq, wto + (size_t)p * 768, 3072, x1, bo, x1,
          nullptr, nullptr, nullptr, 8192, 768, 768);
  }
}